// Round 16
// baseline (175.422 us; speedup 1.0000x reference)
//
#include <hip/hip_runtime.h>

#define B_ 16
#define SST 256
#define SL 48
#define VOCAB 16384
#define D_ 64
#define CH 112
#define WCS (3*128*128)

#define OUT0_ELEMS ((size_t)B_*SST*VOCAB)
#define OUT1_ELEMS (B_*D_*SST)

typedef __attribute__((ext_vector_type(8))) short s8v;
typedef __attribute__((ext_vector_type(4))) float f32x4;

#define MFMA(a,b,c) __builtin_amdgcn_mfma_f32_16x16x32_bf16(a, b, c, 0, 0, 0)

__device__ __forceinline__ void split1(float f, unsigned short* h, unsigned short* l) {
    unsigned u = __float_as_uint(f);
    *h = (unsigned short)(u >> 16);
    float lo = f - __uint_as_float(u & 0xffff0000u);
    *l = (unsigned short)(__float_as_uint(lo) >> 16);
}
__device__ __forceinline__ uint2 split_pack2(float f0, float f1) {
    unsigned u0 = __float_as_uint(f0), u1 = __float_as_uint(f1);
    unsigned hp = (u0 >> 16) | (u1 & 0xffff0000u);
    float l0 = f0 - __uint_as_float(u0 & 0xffff0000u);
    float l1 = f1 - __uint_as_float(u1 & 0xffff0000u);
    unsigned lp = (__float_as_uint(l0) >> 16) | (__float_as_uint(l1) & 0xffff0000u);
    return make_uint2(hp, lp);
}

// ---------------- merged prep: conv weights | shared weights | emb2bf | E ----------------
__global__ __launch_bounds__(256) void prep_kernel(
    const float* __restrict__ w0, const float* __restrict__ w1,
    const float* __restrict__ w2, const float* __restrict__ w3,
    unsigned short* __restrict__ Wch, unsigned short* __restrict__ Wcl,
    const float* __restrict__ cpr1_w, const float* __restrict__ cib_w,
    const float* __restrict__ cpr2_w, const float* __restrict__ cma_w,
    const float* __restrict__ ccf_w, const float* __restrict__ cl0_w,
    unsigned short* __restrict__ Wcomb_h, unsigned short* __restrict__ Wcomb_l,
    unsigned short* __restrict__ W2h, unsigned short* __restrict__ W2l,
    unsigned short* __restrict__ cmah, unsigned short* __restrict__ cmal,
    unsigned short* __restrict__ ccfh, unsigned short* __restrict__ ccfl,
    unsigned short* __restrict__ cl0h, unsigned short* __restrict__ cl0l,
    const float* __restrict__ emb,
    unsigned short* __restrict__ EmbHi, unsigned short* __restrict__ EmbLo,
    const float* __restrict__ ees, const float* __restrict__ cpr1_b,
    const float* __restrict__ cib_b, float* __restrict__ Eb) {
    int blk = blockIdx.x, tid = threadIdx.x;
    unsigned short h, l;
    if (blk < 768) {                    // conv weights: 4*3*128*128
        int gid = blk*256 + tid;
        int c = gid & 127;
        int o = (gid >> 7) & 127;
        int kst = gid >> 14;
        int k = kst % 3, st = kst / 3;
        const float* w = (st == 0) ? w0 : (st == 1) ? w1 : (st == 2) ? w2 : w3;
        float v = (o < CH && c < CH) ? w[o*CH*3 + c*3 + k] : 0.f;
        split1(v, &h, &l);
        Wch[gid] = h; Wcl[gid] = l;
    } else if (blk < 912) {             // shared weights: 36864
        int gid = (blk - 768)*256 + tid;
        if (gid < 8192) {
            int o = gid >> 7, c = gid & 127;
            float v = 0.f;
            if (c < CH) {
                const float* wrow = cpr1_w + o*(2*D_);
                #pragma unroll
                for (int k = 0; k < D_; ++k) v += wrow[k]*cib_w[k*CH + c];
            }
            split1(v, &h, &l); Wcomb_h[gid] = h; Wcomb_l[gid] = l;
        } else if (gid < 12288) {
            int idx = gid - 8192;
            split1(cpr2_w[idx], &h, &l); W2h[idx] = h; W2l[idx] = l;
        } else if (gid < 20480) {
            int idx = gid - 12288;
            int o = idx >> 6;
            float v = (o < CH) ? cma_w[idx] : 0.f;
            split1(v, &h, &l); cmah[idx] = h; cmal[idx] = l;
        } else if (gid < 28672) {
            int idx = gid - 20480;
            int d = idx >> 7, c = idx & 127;
            float v = (c < CH) ? ccf_w[d*CH + c] : 0.f;
            split1(v, &h, &l); ccfh[idx] = h; ccfl[idx] = l;
        } else {
            int idx = gid - 28672;
            int o = idx >> 6;
            float v = (o < CH) ? cl0_w[idx] : 0.f;
            split1(v, &h, &l); cl0h[idx] = h; cl0l[idx] = l;
        }
    } else if (blk < 1936) {            // emb -> bf16 hi/lo (per float4)
        int i = (blk - 912)*256 + tid;
        float4 v = reinterpret_cast<const float4*>(emb)[i];
        ushort4 hh, ll;
        split1(v.x, &hh.x, &ll.x);
        split1(v.y, &hh.y, &ll.y);
        split1(v.z, &hh.z, &ll.z);
        split1(v.w, &hh.w, &ll.w);
        reinterpret_cast<ushort4*>(EmbHi)[i] = hh;
        reinterpret_cast<ushort4*>(EmbLo)[i] = ll;
    } else {                            // E: 4 (b,l) groups of 64 lanes
        __shared__ float ec[4][64];
        int g = tid >> 6, c = tid & 63;
        int bl = (blk - 1936)*4 + g;
        int b = bl / SL, lq = bl % SL;
        ec[g][c] = ees[(b*D_ + c)*SL + lq];
        __syncthreads();
        const float* wrow = cpr1_w + c*(2*D_);
        float acc = cpr1_b[c];
        #pragma unroll
        for (int k = 0; k < D_; ++k) acc += wrow[k]*cib_b[k];
        #pragma unroll
        for (int cc = 0; cc < D_; ++cc) acc += wrow[D_ + cc]*ec[g][cc];
        Eb[(b*SL + lq)*D_ + c] = acc;
    }
}

// ======== h2max wave body (stride-parametrized output) ========
__device__ __forceinline__ void h2max_wave(
    const float* __restrict__ AcRow,
    const float* __restrict__ El,
    const unsigned short* __restrict__ W2h, const unsigned short* __restrict__ W2l,
    int n, int kg, int o_lane, float b2_lane,
    unsigned short* Mmh, unsigned short* Mml, int bs, int stride) {
    float4 a00 = *reinterpret_cast<const float4*>(AcRow + kg*8);
    float4 a01 = *reinterpret_cast<const float4*>(AcRow + kg*8 + 4);
    float4 a10 = *reinterpret_cast<const float4*>(AcRow + 32 + kg*8);
    float4 a11 = *reinterpret_cast<const float4*>(AcRow + 32 + kg*8 + 4);

    f32x4 acc[4][3];
    #pragma unroll
    for (int mt = 0; mt < 4; ++mt)
        #pragma unroll
        for (int lt = 0; lt < 3; ++lt)
            acc[mt][lt] = (f32x4){0.f, 0.f, 0.f, 0.f};

    #pragma unroll
    for (int kt = 0; kt < 2; ++kt) {
        int cc = kt*32 + kg*8;
        float4 aA = (kt == 0) ? a00 : a10;
        float4 aB = (kt == 0) ? a01 : a11;
        s8v a2h[4], a2l[4];
        #pragma unroll
        for (int mt = 0; mt < 4; ++mt) {
            a2h[mt] = *(const s8v*)&W2h[(mt*16 + n)*64 + cc];
            a2l[mt] = *(const s8v*)&W2l[(mt*16 + n)*64 + cc];
        }
        #pragma unroll
        for (int lt = 0; lt < 3; ++lt) {
            const float* ep = &El[(lt*16 + n)*68 + cc];
            float4 e0 = *reinterpret_cast<const float4*>(ep);
            float4 e1 = *reinterpret_cast<const float4*>(ep + 4);
            float h0 = fmaxf(aA.x + e0.x, 0.f);
            float h1 = fmaxf(aA.y + e0.y, 0.f);
            float h2 = fmaxf(aA.z + e0.z, 0.f);
            float h3 = fmaxf(aA.w + e0.w, 0.f);
            float h4 = fmaxf(aB.x + e1.x, 0.f);
            float h5 = fmaxf(aB.y + e1.y, 0.f);
            float h6 = fmaxf(aB.z + e1.z, 0.f);
            float h7 = fmaxf(aB.w + e1.w, 0.f);
            uint2 q0 = split_pack2(h0, h1);
            uint2 q1 = split_pack2(h2, h3);
            uint2 q2 = split_pack2(h4, h5);
            uint2 q3 = split_pack2(h6, h7);
            union { unsigned u[4]; s8v v; } Bh, Bl;
            Bh.u[0] = q0.x; Bh.u[1] = q1.x; Bh.u[2] = q2.x; Bh.u[3] = q3.x;
            Bl.u[0] = q0.y; Bl.u[1] = q1.y; Bl.u[2] = q2.y; Bl.u[3] = q3.y;
            #pragma unroll
            for (int mt = 0; mt < 4; ++mt) {
                acc[mt][lt] = MFMA(a2h[mt], Bh.v, acc[mt][lt]);
                acc[mt][lt] = MFMA(a2h[mt], Bl.v, acc[mt][lt]);
                acc[mt][lt] = MFMA(a2l[mt], Bh.v, acc[mt][lt]);
            }
        }
    }

    float mx[16];
    #pragma unroll
    for (int mt = 0; mt < 4; ++mt)
        #pragma unroll
        for (int r = 0; r < 4; ++r)
            mx[mt*4 + r] = fmaxf(fmaxf(acc[mt][0][r], acc[mt][1][r]), acc[mt][2][r]);
    #pragma unroll
    for (int step = 0; step < 4; ++step) {
        int msk = 1 << step;
        #pragma unroll
        for (int i = 0; i < 16; ++i)
            mx[i] = fmaxf(mx[i], __shfl_xor(mx[i], msk));
    }
    float sel = mx[0];
    #pragma unroll
    for (int i = 1; i < 16; ++i)
        sel = (n == i) ? mx[i] : sel;
    float mval = fmaxf(sel + b2_lane, 0.f);
    unsigned short mh, ml; split1(mval, &mh, &ml);
    Mmh[bs*stride + o_lane] = mh;
    Mml[bs*stride + o_lane] = ml;
}

// ---------------- stage1: gather+cl0 head, conv3+Wcomb, fused h2max (r10) ----------------
__global__ __launch_bounds__(512) void stage1_kernel(
    const int* __restrict__ x, const float* __restrict__ emb,
    const unsigned short* __restrict__ cl0h, const unsigned short* __restrict__ cl0l,
    const float* __restrict__ cl0_b,
    const unsigned short* __restrict__ Wch, const unsigned short* __restrict__ Wcl,
    const float* __restrict__ conv_b,
    const unsigned short* __restrict__ Wcombh, const unsigned short* __restrict__ Wcombl,
    const float* __restrict__ Eb,
    const unsigned short* __restrict__ W2h, const unsigned short* __restrict__ W2l,
    const float* __restrict__ cpr2_b,
    float* __restrict__ pre_d, float* __restrict__ xc_g,
    unsigned short* __restrict__ Mmh, unsigned short* __restrict__ Mml) {
    int b = blockIdx.x >> 4, s0 = (blockIdx.x & 15) << 4;
    int tid = threadIdx.x, w = tid >> 6, lane = tid & 63, n = lane & 15, kg = lane >> 4;

    __shared__ unsigned short Eg_h[18*72], Eg_l[18*72];
    __shared__ unsigned short Tt_h[18*136], Tt_l[18*136];
    __shared__ unsigned short Xt_h[16*136], Xt_l[16*136];
    __shared__ float El[48*68];
    __shared__ float AcT[16*68];

    for (int idx = tid; idx < 288; idx += 512) {
        int si = idx >> 4, c4 = (idx & 15)*4;
        int s = s0 - 2 + si;
        float4 v = make_float4(0.f, 0.f, 0.f, 0.f);
        if (s >= 0) {
            int tok = x[b*SST + s];
            v = *reinterpret_cast<const float4*>(&emb[tok*D_ + c4]);
        }
        ushort4 h, l;
        split1(v.x, &h.x, &l.x); split1(v.y, &h.y, &l.y);
        split1(v.z, &h.z, &l.z); split1(v.w, &h.w, &l.w);
        *reinterpret_cast<ushort4*>(&Eg_h[si*72 + c4]) = h;
        *reinterpret_cast<ushort4*>(&Eg_l[si*72 + c4]) = l;
        if (si >= 2) {
            pre_d[(b*D_ + c4+0)*SST + s] = v.x;
            pre_d[(b*D_ + c4+1)*SST + s] = v.y;
            pre_d[(b*D_ + c4+2)*SST + s] = v.z;
            pre_d[(b*D_ + c4+3)*SST + s] = v.w;
        }
    }
    for (int idx = tid; idx < 768; idx += 512) {
        int l = idx >> 4, c4 = (idx & 15)*4;
        *reinterpret_cast<float4*>(&El[l*68 + c4]) =
            *reinterpret_cast<const float4*>(&Eb[(b*SL + l)*64 + c4]);
    }
    __syncthreads();

    int ob = w*16 + kg*4;
    #pragma unroll
    for (int ct = 0; ct < 2; ++ct) {
        int si = ct*2 + n;
        f32x4 tv = {0.f, 0.f, 0.f, 0.f};
        #pragma unroll
        for (int kt = 0; kt < 2; ++kt) {
            int cc = kt*32 + kg*8;
            s8v bh = *(const s8v*)&Eg_h[si*72 + cc];
            s8v bl = *(const s8v*)&Eg_l[si*72 + cc];
            int ai = (w*16 + n)*64 + cc;
            s8v ah = *(const s8v*)&cl0h[ai];
            s8v al = *(const s8v*)&cl0l[ai];
            tv = MFMA(ah, bh, tv); tv = MFMA(ah, bl, tv); tv = MFMA(al, bh, tv);
        }
        int s = s0 - 2 + si;
        float r0 = 0.f, r1 = 0.f, r2 = 0.f, r3 = 0.f;
        if (s >= 0) {
            r0 = tv[0] + ((ob+0 < CH) ? cl0_b[ob+0] : 0.f);
            r1 = tv[1] + ((ob+1 < CH) ? cl0_b[ob+1] : 0.f);
            r2 = tv[2] + ((ob+2 < CH) ? cl0_b[ob+2] : 0.f);
            r3 = tv[3] + ((ob+3 < CH) ? cl0_b[ob+3] : 0.f);
        }
        uint2 p01 = split_pack2(r0, r1), p23 = split_pack2(r2, r3);
        *reinterpret_cast<uint2*>(&Tt_h[si*136 + ob]) = make_uint2(p01.x, p23.x);
        *reinterpret_cast<uint2*>(&Tt_l[si*136 + ob]) = make_uint2(p01.y, p23.y);
    }
    __syncthreads();

    f32x4 xcv = {0.f, 0.f, 0.f, 0.f};
    #pragma unroll
    for (int k = 0; k < 3; ++k)
        #pragma unroll
        for (int kt = 0; kt < 4; ++kt) {
            int cc = kt*32 + kg*8;
            s8v bh = *(const s8v*)&Tt_h[(n + k)*136 + cc];
            s8v bl = *(const s8v*)&Tt_l[(n + k)*136 + cc];
            int ai = (k*128 + w*16 + n)*128 + cc;
            s8v ah = *(const s8v*)&Wch[ai];
            s8v al = *(const s8v*)&Wcl[ai];
            xcv = MFMA(ah, bh, xcv); xcv = MFMA(ah, bl, xcv); xcv = MFMA(al, bh, xcv);
        }
    #pragma unroll
    for (int r = 0; r < 4; ++r) {
        float cb = (ob + r < CH) ? conv_b[ob + r] : 0.f;
        xcv[r] = fmaxf(xcv[r] + cb, 0.f);
    }
    {
        uint2 p01 = split_pack2(xcv[0], xcv[1]), p23 = split_pack2(xcv[2], xcv[3]);
        *reinterpret_cast<uint2*>(&Xt_h[n*136 + ob]) = make_uint2(p01.x, p23.x);
        *reinterpret_cast<uint2*>(&Xt_l[n*136 + ob]) = make_uint2(p01.y, p23.y);
        *reinterpret_cast<float4*>(&xc_g[(b*SST + s0 + n)*128 + ob]) =
            make_float4(xcv[0], xcv[1], xcv[2], xcv[3]);
    }
    __syncthreads();

    if (w < 4) {
        f32x4 acc = {0.f, 0.f, 0.f, 0.f};
        #pragma unroll
        for (int kt = 0; kt < 4; ++kt) {
            int cc = kt*32 + kg*8;
            int ai = (w*16 + n)*128 + cc;
            s8v ah = *(const s8v*)&Wcombh[ai];
            s8v al = *(const s8v*)&Wcombl[ai];
            s8v bh = *(const s8v*)&Xt_h[n*136 + cc];
            s8v bl = *(const s8v*)&Xt_l[n*136 + cc];
            acc = MFMA(ah, bh, acc); acc = MFMA(ah, bl, acc); acc = MFMA(al, bh, acc);
        }
        *reinterpret_cast<float4*>(&AcT[n*68 + w*16 + kg*4]) =
            make_float4(acc[0], acc[1], acc[2], acc[3]);
    }
    __syncthreads();

    int o_lane = ((n >> 2) << 4) + (kg << 2) + (n & 3);
    float b2_lane = cpr2_b[o_lane];
    #pragma unroll
    for (int si = 0; si < 2; ++si) {
        int s = w*2 + si;
        h2max_wave(&AcT[s*68], El, W2h, W2l, n, kg, o_lane, b2_lane,
                   Mmh, Mml, b*SST + s0 + s, 64);
    }
}

// ---------------- stageM: cma@Mm+xc head, conv3+Wcomb, fused h2max (r10) ----------------
__global__ __launch_bounds__(512) void stagem_kernel(
    const unsigned short* __restrict__ Mmh_in, const unsigned short* __restrict__ Mml_in,
    const unsigned short* __restrict__ cmah, const unsigned short* __restrict__ cmal,
    const float* __restrict__ cma_b, const float* __restrict__ xc_prev,
    const unsigned short* __restrict__ Wch, const unsigned short* __restrict__ Wcl,
    const float* __restrict__ conv_b,
    const unsigned short* __restrict__ Wcombh, const unsigned short* __restrict__ Wcombl,
    const float* __restrict__ Eb,
    const unsigned short* __restrict__ W2h, const unsigned short* __restrict__ W2l,
    const float* __restrict__ cpr2_b,
    float* __restrict__ xc_g,
    unsigned short* __restrict__ Mmh_out, unsigned short* __restrict__ Mml_out) {
    int b = blockIdx.x >> 4, s0 = (blockIdx.x & 15) << 4;
    int tid = threadIdx.x, w = tid >> 6, lane = tid & 63, n = lane & 15, kg = lane >> 4;

    __shared__ unsigned short Eg_h[18*72], Eg_l[18*72];
    __shared__ unsigned short Tt_h[18*136], Tt_l[18*136];
    __shared__ unsigned short Xt_h[16*136], Xt_l[16*136];
    __shared__ float El[48*68];
    __shared__ float AcT[16*68];

    for (int idx = tid; idx < 288; idx += 512) {
        int si = idx >> 4, c4 = (idx & 15)*4;
        int s = s0 - 2 + si;
        uint2 h = make_uint2(0, 0), l = make_uint2(0, 0);
        if (s >= 0) {
            h = *reinterpret_cast<const uint2*>(&Mmh_in[(b*SST + s)*64 + c4]);
            l = *reinterpret_cast<const uint2*>(&Mml_in[(b*SST + s)*64 + c4]);
        }
        *reinterpret_cast<uint2*>(&Eg_h[si*72 + c4]) = h;
        *reinterpret_cast<uint2*>(&Eg_l[si*72 + c4]) = l;
    }
    for (int idx = tid; idx < 768; idx += 512) {
        int l = idx >> 4, c4 = (idx & 15)*4;
        *reinterpret_cast<float4*>(&El[l*68 + c4]) =
            *reinterpret_cast<const float4*>(&Eb[(b*SL + l)*64 + c4]);
    }
    __syncthreads();

    int ob = w*16 + kg*4;
    #pragma unroll
    for (int ct = 0; ct < 2; ++ct) {
        int si = ct*2 + n;
        f32x4 tv = {0.f, 0.f, 0.f, 0.f};
        #pragma unroll
        for (int kt = 0; kt < 2; ++kt) {
            int cc = kt*32 + kg*8;
            s8v bh = *(const s8v*)&Eg_h[si*72 + cc];
            s8v bl = *(const s8v*)&Eg_l[si*72 + cc];
            int ai = (w*16 + n)*64 + cc;
            s8v ah = *(const s8v*)&cmah[ai];
            s8v al = *(const s8v*)&cmal[ai];
            tv = MFMA(ah, bh, tv); tv = MFMA(ah, bl, tv); tv = MFMA(al, bh, tv);
        }
        int s = s0 - 2 + si;
        float r0 = 0.f, r1 = 0.f, r2 = 0.f, r3 = 0.f;
        if (s >= 0) {
            float4 xr = *reinterpret_cast<const float4*>(&xc_prev[(b*SST + s)*128 + ob]);
            r0 = tv[0] + ((ob+0 < CH) ? cma_b[ob+0] : 0.f) + xr.x;
            r1 = tv[1] + ((ob+1 < CH) ? cma_b[ob+1] : 0.f) + xr.y;
            r2 = tv[2] + ((ob+2 < CH) ? cma_b[ob+2] : 0.f) + xr.z;
            r3 = tv[3] + ((ob+3 < CH) ? cma_b[ob+3] : 0.f) + xr.w;
        }
        uint2 p01 = split_pack2(r0, r1), p23 = split_pack2(r2, r3);
        *reinterpret_cast<uint2*>(&Tt_h[si*136 + ob]) = make_uint2(p01.x, p23.x);
        *reinterpret_cast<uint2*>(&Tt_l[si*136 + ob]) = make_uint2(p01.y, p23.y);
    }
    __syncthreads();

    f32x4 xcv = {0.f, 0.f, 0.f, 0.f};
    #pragma unroll
    for (int k = 0; k < 3; ++k)
        #pragma unroll
        for (int kt = 0; kt < 4; ++kt) {
            int cc = kt*32 + kg*8;
            s8v bh = *(const s8v*)&Tt_h[(n + k)*136 + cc];
            s8v bl = *(const s8v*)&Tt_l[(n + k)*136 + cc];
            int ai = (k*128 + w*16 + n)*128 + cc;
            s8v ah = *(const s8v*)&Wch[ai];
            s8v al = *(const s8v*)&Wcl[ai];
            xcv = MFMA(ah, bh, xcv); xcv = MFMA(ah, bl, xcv); xcv = MFMA(al, bh, xcv);
        }
    #pragma unroll
    for (int r = 0; r < 4; ++r) {
        float cb = (ob + r < CH) ? conv_b[ob + r] : 0.f;
        xcv[r] = fmaxf(xcv[r] + cb, 0.f);
    }
    {
        uint2 p01 = split_pack2(xcv[0], xcv[1]), p23 = split_pack2(xcv[2], xcv[3]);
        *reinterpret_cast<uint2*>(&Xt_h[n*136 + ob]) = make_uint2(p01.x, p23.x);
        *reinterpret_cast<uint2*>(&Xt_l[n*136 + ob]) = make_uint2(p01.y, p23.y);
        *reinterpret_cast<float4*>(&xc_g[(b*SST + s0 + n)*128 + ob]) =
            make_float4(xcv[0], xcv[1], xcv[2], xcv[3]);
    }
    __syncthreads();

    if (w < 4) {
        f32x4 acc = {0.f, 0.f, 0.f, 0.f};
        #pragma unroll
        for (int kt = 0; kt < 4; ++kt) {
            int cc = kt*32 + kg*8;
            int ai = (w*16 + n)*128 + cc;
            s8v ah = *(const s8v*)&Wcombh[ai];
            s8v al = *(const s8v*)&Wcombl[ai];
            s8v bh = *(const s8v*)&Xt_h[n*136 + cc];
            s8v bl = *(const s8v*)&Xt_l[n*136 + cc];
            acc = MFMA(ah, bh, acc); acc = MFMA(ah, bl, acc); acc = MFMA(al, bh, acc);
        }
        *reinterpret_cast<float4*>(&AcT[n*68 + w*16 + kg*4]) =
            make_float4(acc[0], acc[1], acc[2], acc[3]);
    }
    __syncthreads();

    int o_lane = ((n >> 2) << 4) + (kg << 2) + (n & 3);
    float b2_lane = cpr2_b[o_lane];
    #pragma unroll
    for (int si = 0; si < 2; ++si) {
        int s = w*2 + si;
        h2max_wave(&AcT[s*68], El, W2h, W2l, n, kg, o_lane, b2_lane,
                   Mmh_out, Mml_out, b*SST + s0 + s, 64);
    }
}

// ------- stage4: stageM body + fused cmaccf tail (Mm in LDS, xcv in regs) -------
__global__ __launch_bounds__(512) void stage4_kernel(
    const unsigned short* __restrict__ Mmh_in, const unsigned short* __restrict__ Mml_in,
    const unsigned short* __restrict__ cmah, const unsigned short* __restrict__ cmal,
    const float* __restrict__ cma_b, const float* __restrict__ xc_prev,
    const unsigned short* __restrict__ Wch, const unsigned short* __restrict__ Wcl,
    const float* __restrict__ conv_b,
    const unsigned short* __restrict__ Wcombh, const unsigned short* __restrict__ Wcombl,
    const float* __restrict__ Eb,
    const unsigned short* __restrict__ W2h, const unsigned short* __restrict__ W2l,
    const float* __restrict__ cpr2_b,
    const unsigned short* __restrict__ ccfh, const unsigned short* __restrict__ ccfl,
    const float* __restrict__ ccf_b,
    float* __restrict__ ccf_out,
    unsigned short* __restrict__ Ahi, unsigned short* __restrict__ Alo) {
    int b = blockIdx.x >> 4, s0 = (blockIdx.x & 15) << 4;
    int tid = threadIdx.x, w = tid >> 6, lane = tid & 63, n = lane & 15, kg = lane >> 4;

    __shared__ unsigned short Eg_h[18*72], Eg_l[18*72];    // reused as Mm LDS later
    __shared__ unsigned short Tt_h[18*136], Tt_l[18*136];  // reused as t4 LDS later
    __shared__ unsigned short Xt_h[16*136], Xt_l[16*136];
    __shared__ float El[48*68];
    __shared__ float AcT[16*68];

    for (int idx = tid; idx < 288; idx += 512) {
        int si = idx >> 4, c4 = (idx & 15)*4;
        int s = s0 - 2 + si;
        uint2 h = make_uint2(0, 0), l = make_uint2(0, 0);
        if (s >= 0) {
            h = *reinterpret_cast<const uint2*>(&Mmh_in[(b*SST + s)*64 + c4]);
            l = *reinterpret_cast<const uint2*>(&Mml_in[(b*SST + s)*64 + c4]);
        }
        *reinterpret_cast<uint2*>(&Eg_h[si*72 + c4]) = h;
        *reinterpret_cast<uint2*>(&Eg_l[si*72 + c4]) = l;
    }
    for (int idx = tid; idx < 768; idx += 512) {
        int l = idx >> 4, c4 = (idx & 15)*4;
        *reinterpret_cast<float4*>(&El[l*68 + c4]) =
            *reinterpret_cast<const float4*>(&Eb[(b*SL + l)*64 + c4]);
    }
    __syncthreads();

    int ob = w*16 + kg*4;
    #pragma unroll
    for (int ct = 0; ct < 2; ++ct) {
        int si = ct*2 + n;
        f32x4 tv = {0.f, 0.f, 0.f, 0.f};
        #pragma unroll
        for (int kt = 0; kt < 2; ++kt) {
            int cc = kt*32 + kg*8;
            s8v bh = *(const s8v*)&Eg_h[si*72 + cc];
            s8v bl = *(const s8v*)&Eg_l[si*72 + cc];
            int ai = (w*16 + n)*64 + cc;
            s8v ah = *(const s8v*)&cmah[ai];
            s8v al = *(const s8v*)&cmal[ai];
            tv = MFMA(ah, bh, tv); tv = MFMA(ah, bl, tv); tv = MFMA(al, bh, tv);
        }
        int s = s0 - 2 + si;
        float r0 = 0.f, r1 = 0.f, r2 = 0.f, r3 = 0.f;
        if (s >= 0) {
            float4 xr = *reinterpret_cast<const float4*>(&xc_prev[(b*SST + s)*128 + ob]);
            r0 = tv[0] + ((ob+0 < CH) ? cma_b[ob+0] : 0.f) + xr.x;
            r1 = tv[1] + ((ob+1 < CH) ? cma_b[ob+1] : 0.f) + xr.y;
            r2 = tv[2] + ((ob+2 < CH) ? cma_b[ob+2] : 0.f) + xr.z;
            r3 = tv[3] + ((ob+3 < CH) ? cma_b[ob+3] : 0.f) + xr.w;
        }
        uint2 p01 = split_pack2(r0, r1), p23 = split_pack2(r2, r3);
        *reinterpret_cast<uint2*>(&Tt_h[si*136 + ob]) = make_uint2(p01.x, p23.x);
        *reinterpret_cast<uint2*>(&Tt_l[si*136 + ob]) = make_uint2(p01.y, p23.y);
    }
    __syncthreads();

    f32x4 xcv = {0.f, 0.f, 0.f, 0.f};
    #pragma unroll
    for (int k = 0; k < 3; ++k)
        #pragma unroll
        for (int kt = 0; kt < 4; ++kt) {
            int cc = kt*32 + kg*8;
            s8v bh = *(const s8v*)&Tt_h[(n + k)*136 + cc];
            s8v bl = *(const s8v*)&Tt_l[(n + k)*136 + cc];
            int ai = (k*128 + w*16 + n)*128 + cc;
            s8v ah = *(const s8v*)&Wch[ai];
            s8v al = *(const s8v*)&Wcl[ai];
            xcv = MFMA(ah, bh, xcv); xcv = MFMA(ah, bl, xcv); xcv = MFMA(al, bh, xcv);
        }
    #pragma unroll
    for (int r = 0; r < 4; ++r) {
        float cb = (ob + r < CH) ? conv_b[ob + r] : 0.f;
        xcv[r] = fmaxf(xcv[r] + cb, 0.f);
    }
    {
        uint2 p01 = split_pack2(xcv[0], xcv[1]), p23 = split_pack2(xcv[2], xcv[3]);
        *reinterpret_cast<uint2*>(&Xt_h[n*136 + ob]) = make_uint2(p01.x, p23.x);
        *reinterpret_cast<uint2*>(&Xt_l[n*136 + ob]) = make_uint2(p01.y, p23.y);
        // no xc_g global store: consumed in-registers by the t4 tail below
    }
    __syncthreads();

    if (w < 4) {
        f32x4 acc = {0.f, 0.f, 0.f, 0.f};
        #pragma unroll
        for (int kt = 0; kt < 4; ++kt) {
            int cc = kt*32 + kg*8;
            int ai = (w*16 + n)*128 + cc;
            s8v ah = *(const s8v*)&Wcombh[ai];
            s8v al = *(const s8v*)&Wcombl[ai];
            s8v bh = *(const s8v*)&Xt_h[n*136 + cc];
            s8v bl = *(const s8v*)&Xt_l[n*136 + cc];
            acc = MFMA(ah, bh, acc); acc = MFMA(ah, bl, acc); acc = MFMA(al, bh, acc);
        }
        *reinterpret_cast<float4*>(&AcT[n*68 + w*16 + kg*4]) =
            make_float4(acc[0], acc[1], acc[2], acc[3]);
    }
    __syncthreads();

    // h2max -> Mm in LDS (reuse Eg space; stride 72, local s index)
    int o_lane = ((n >> 2) << 4) + (kg << 2) + (n & 3);
    float b2_lane = cpr2_b[o_lane];
    #pragma unroll
    for (int si = 0; si < 2; ++si) {
        int s = w*2 + si;
        h2max_wave(&AcT[s*68], El, W2h, W2l, n, kg, o_lane, b2_lane,
                   Eg_h, Eg_l, s, 72);
    }
    __syncthreads();

    // t4 = cma @ Mm + cma_b + xconv  (wave w -> o-tile w; col = n) -> Tt reuse
    {
        f32x4 tv = {0.f, 0.f, 0.f, 0.f};
        #pragma unroll
        for (int kt = 0; kt < 2; ++kt) {
            int cc = kt*32 + kg*8;
            s8v bh = *(const s8v*)&Eg_h[n*72 + cc];
            s8v bl = *(const s8v*)&Eg_l[n*72 + cc];
            int ai = (w*16 + n)*64 + cc;
            s8v ah = *(const s8v*)&cmah[ai];
            s8v al = *(const s8v*)&cmal[ai];
            tv = MFMA(ah, bh, tv); tv = MFMA(ah, bl, tv); tv = MFMA(al, bh, tv);
        }
        float r0 = tv[0] + ((ob+0 < CH) ? cma_b[ob+0] : 0.f) + xcv[0];
        float r1 = tv[1] + ((ob+1 < CH) ? cma_b[ob+1] : 0.f) + xcv[1];
        float r2 = tv[2] + ((ob+2 < CH) ? cma_b[ob+2] : 0.f) + xcv[2];
        float r3 = tv[3] + ((ob+3 < CH) ? cma_b[ob+3] : 0.f) + xcv[3];
        uint2 p01 = split_pack2(r0, r1), p23 = split_pack2(r2, r3);
        *reinterpret_cast<uint2*>(&Tt_h[n*136 + ob]) = make_uint2(p01.x, p23.x);
        *reinterpret_cast<uint2*>(&Tt_l[n*136 + ob]) = make_uint2(p01.y, p23.y);
    }
    __syncthreads();

    // ccf = ccf_w @ t4 + ccf_b  (waves 0-3, d-tile w)
    if (w < 4) {
        f32x4 acc = {0.f, 0.f, 0.f, 0.f};
        #pragma unroll
        for (int kt = 0; kt < 4; ++kt) {
            int cc = kt*32 + kg*8;
            int ai = (w*16 + n)*128 + cc;
            s8v ah = *(const s8v*)&ccfh[ai];
            s8v al = *(const s8v*)&ccfl[ai];
            s8v bh = *(const s8v*)&Tt_h[n*136 + cc];
            s8v bl = *(const s8v*)&Tt_l[n*136 + cc];
            acc = MFMA(ah, bh, acc); acc = MFMA(ah, bl, acc); acc = MFMA(al, bh, acc);
        }
        int d0 = w*16 + kg*4, s = s0 + n;
        float v0 = acc[0] + ccf_b[d0+0];
        float v1 = acc[1] + ccf_b[d0+1];
        float v2 = acc[2] + ccf_b[d0+2];
        float v3 = acc[3] + ccf_b[d0+3];
        ccf_out[(b*D_ + d0+0)*SST + s] = v0;
        ccf_out[(b*D_ + d0+1)*SST + s] = v1;
        ccf_out[(b*D_ + d0+2)*SST + s] = v2;
        ccf_out[(b*D_ + d0+3)*SST + s] = v3;
        uint2 p01 = split_pack2(v0, v1), p23 = split_pack2(v2, v3);
        *reinterpret_cast<uint2*>(&Ahi[(b*SST + s)*64 + d0]) = make_uint2(p01.x, p23.x);
        *reinterpret_cast<uint2*>(&Alo[(b*SST + s)*64 + d0]) = make_uint2(p01.y, p23.y);
    }
}

// ---------------- logits: r10-best + XCD-contiguous block swizzle ----------------
// Dispatch round-robins blocks across 8 XCDs; with the identity mapping,
// v-adjacent tiles land on different private L2s, so each XCD's write-backs
// scatter 512B chunks at 4KB stride across DRAM pages. The bijective swizzle
// (grid 4096 % 8 == 0) gives XCD k the contiguous logical range [k*512,(k+1)*512)
// = mtiles [4k,4k+4) x all ntiles = one compact 32MB output span per XCD-L2.
__global__ __launch_bounds__(256) void logits_mfma_kernel(
    const unsigned short* __restrict__ Ahi,
    const unsigned short* __restrict__ Alo,
    const unsigned short* __restrict__ Bhi,
    const unsigned short* __restrict__ Blo,
    const float* __restrict__ fffb,
    float* __restrict__ out) {
    int bid = blockIdx.x;
    int swz = (bid & 7)*512 + (bid >> 3);   // XCD-contiguous logical tile id
    int ntile = swz & 127;
    int mtile = swz >> 7;
    int wid = threadIdx.x >> 6;
    int lane = threadIdx.x & 63;
    int wm = wid >> 1, wn = wid & 1;
    int m0 = mtile*128 + wm*64;
    int v0 = ntile*128 + wn*64;
    int row16 = lane & 15, kg = lane >> 4;

    const short* Ah = (const short*)Ahi;
    const short* Al = (const short*)Alo;
    const short* Bh = (const short*)Bhi;
    const short* Bl = (const short*)Blo;

    f32x4 acc[4][4];
    #pragma unroll
    for (int mi = 0; mi < 4; ++mi)
        #pragma unroll
        for (int ni = 0; ni < 4; ++ni)
            acc[mi][ni] = (f32x4){0.f, 0.f, 0.f, 0.f};

    #pragma unroll
    for (int kk = 0; kk < 2; ++kk) {
        int koff = kk*32 + kg*8;
        s8v ah[4], al[4], bh[4], bl[4];
        #pragma unroll
        for (int mi = 0; mi < 4; ++mi) {
            int r = (m0 + mi*16 + row16)*D_ + koff;
            ah[mi] = *reinterpret_cast<const s8v*>(Ah + r);
            al[mi] = *reinterpret_cast<const s8v*>(Al + r);
        }
        #pragma unroll
        for (int ni = 0; ni < 4; ++ni) {
            int r = (v0 + ni*16 + row16)*D_ + koff;
            bh[ni] = *reinterpret_cast<const s8v*>(Bh + r);
            bl[ni] = *reinterpret_cast<const s8v*>(Bl + r);
        }
        #pragma unroll
        for (int mi = 0; mi < 4; ++mi)
            #pragma unroll
            for (int ni = 0; ni < 4; ++ni) {
                acc[mi][ni] = MFMA(ah[mi], bh[ni], acc[mi][ni]);
                acc[mi][ni] = MFMA(ah[mi], bl[ni], acc[mi][ni]);
                acc[mi][ni] = MFMA(al[mi], bh[ni], acc[mi][ni]);
            }
    }

    float fb[4];
    #pragma unroll
    for (int ni = 0; ni < 4; ++ni) fb[ni] = fffb[v0 + ni*16 + row16];

    #pragma unroll
    for (int mi = 0; mi < 4; ++mi) {
        #pragma unroll
        for (int r = 0; r < 4; ++r) {
            size_t rowbase = (size_t)(m0 + mi*16 + kg*4 + r)*VOCAB;
            #pragma unroll
            for (int ni = 0; ni < 4; ++ni) {
                out[rowbase + v0 + ni*16 + row16] = acc[mi][ni][r] + fb[ni];
            }
        }
    }
}

extern "C" void kernel_launch(void* const* d_in, const int* in_sizes, int n_in,
                              void* d_out, int out_size, void* d_ws, size_t ws_size,
                              hipStream_t stream) {
    const int*   x     = (const int*)d_in[0];
    const float* ees   = (const float*)d_in[1];
    const float* emb   = (const float*)d_in[2];
    const float* cl0_w = (const float*)d_in[3];
    const float* cl0_b = (const float*)d_in[4];
    const float* cl1_w = (const float*)d_in[5];
    const float* cl1_b = (const float*)d_in[6];
    const float* claa_w= (const float*)d_in[7];
    const float* claa_b= (const float*)d_in[8];
    const float* clfa_w= (const float*)d_in[9];
    const float* clfa_b= (const float*)d_in[10];
    const float* ccac_w= (const float*)d_in[11];
    const float* ccac_b= (const float*)d_in[12];
    const float* cib_w = (const float*)d_in[13];
    const float* cib_b = (const float*)d_in[14];
    const float* cpr1_w= (const float*)d_in[15];
    const float* cpr1_b= (const float*)d_in[16];
    const float* cpr2_w= (const float*)d_in[17];
    const float* cpr2_b= (const float*)d_in[18];
    const float* cma_w = (const float*)d_in[19];
    const float* cma_b = (const float*)d_in[20];
    const float* ccf_w = (const float*)d_in[21];
    const float* ccf_b = (const float*)d_in[22];
    const float* fff_b = (const float*)d_in[23];

    float* out = (float*)d_out;
    float* out_pre = out + OUT0_ELEMS;
    float* out_ccf = out_pre + OUT1_ELEMS;

    unsigned short* EmbHi = (unsigned short*)d_ws;
    unsigned short* EmbLo = EmbHi + VOCAB*D_;
    unsigned short* Ahi   = EmbLo + VOCAB*D_;
    unsigned short* Alo   = Ahi + B_*SST*D_;

    char* sc = (char*)d_out + (size_t)16*1024*1024;
    float*          Eb    = (float*)sc;            sc += B_*SL*D_*4;
    unsigned short* Wch   = (unsigned short*)sc;   sc += 4*3*128*128*2;
    unsigned short* Wcl   = (unsigned short*)sc;   sc += 4*3*128*128*2;
    unsigned short* Wcombh= (unsigned short*)sc;   sc += 64*128*2;
    unsigned short* Wcombl= (unsigned short*)sc;   sc += 64*128*2;
    unsigned short* W2h   = (unsigned short*)sc;   sc += 64*64*2;
    unsigned short* W2l   = (unsigned short*)sc;   sc += 64*64*2;
    unsigned short* cmah  = (unsigned short*)sc;   sc += 128*64*2;
    unsigned short* cmal  = (unsigned short*)sc;   sc += 128*64*2;
    unsigned short* ccfh  = (unsigned short*)sc;   sc += 64*128*2;
    unsigned short* ccfl  = (unsigned short*)sc;   sc += 64*128*2;
    unsigned short* cl0h  = (unsigned short*)sc;   sc += 128*64*2;
    unsigned short* cl0l  = (unsigned short*)sc;   sc += 128*64*2;
    float*          xc_a  = (float*)sc;            sc += (size_t)B_*SST*128*4;
    float*          xc_b  = (float*)sc;            sc += (size_t)B_*SST*128*4;
    unsigned short* Mmh   = (unsigned short*)sc;   sc += B_*SST*64*2;
    unsigned short* Mml   = (unsigned short*)sc;   sc += B_*SST*64*2;

    // merged prep: conv(768) | shared(144) | emb2bf(1024) | E(192)
    prep_kernel<<<2128, 256, 0, stream>>>(
        cl1_w, claa_w, clfa_w, ccac_w, Wch, Wcl,
        cpr1_w, cib_w, cpr2_w, cma_w, ccf_w, cl0_w,
        Wcombh, Wcombl, W2h, W2l, cmah, cmal, ccfh, ccfl, cl0h, cl0l,
        emb, EmbHi, EmbLo,
        ees, cpr1_b, cib_b, Eb);

    stage1_kernel<<<256, 512, 0, stream>>>(x, emb, cl0h, cl0l, cl0_b,
        Wch + 0*WCS, Wcl + 0*WCS, cl1_b, Wcombh, Wcombl, Eb, W2h, W2l, cpr2_b,
        out_pre, xc_a, Mmh, Mml);
    stagem_kernel<<<256, 512, 0, stream>>>(Mmh, Mml, cmah, cmal, cma_b, xc_a,
        Wch + 1*WCS, Wcl + 1*WCS, claa_b, Wcombh, Wcombl, Eb, W2h, W2l, cpr2_b,
        xc_b, Mmh, Mml);
    stagem_kernel<<<256, 512, 0, stream>>>(Mmh, Mml, cmah, cmal, cma_b, xc_b,
        Wch + 2*WCS, Wcl + 2*WCS, clfa_b, Wcombh, Wcombl, Eb, W2h, W2l, cpr2_b,
        xc_a, Mmh, Mml);
    stage4_kernel<<<256, 512, 0, stream>>>(Mmh, Mml, cmah, cmal, cma_b, xc_a,
        Wch + 3*WCS, Wcl + 3*WCS, ccac_b, Wcombh, Wcombl, Eb, W2h, W2l, cpr2_b,
        ccfh, ccfl, ccf_b, out_ccf, Ahi, Alo);

    logits_mfma_kernel<<<(B_*SST/128)*(VOCAB/128), 256, 0, stream>>>(
        Ahi, Alo, EmbHi, EmbLo, fff_b, out);
}

// Round 17
// 167.477 us; speedup vs baseline: 1.0474x; 1.0474x over previous
//
#include <hip/hip_runtime.h>

#define B_ 16
#define SST 256
#define SL 48
#define VOCAB 16384
#define D_ 64
#define CH 112
#define WCS (3*128*128)

#define OUT0_ELEMS ((size_t)B_*SST*VOCAB)
#define OUT1_ELEMS (B_*D_*SST)

typedef __attribute__((ext_vector_type(8))) short s8v;
typedef __attribute__((ext_vector_type(4))) float f32x4;

#define MFMA(a,b,c) __builtin_amdgcn_mfma_f32_16x16x32_bf16(a, b, c, 0, 0, 0)

__device__ __forceinline__ void split1(float f, unsigned short* h, unsigned short* l) {
    unsigned u = __float_as_uint(f);
    *h = (unsigned short)(u >> 16);
    float lo = f - __uint_as_float(u & 0xffff0000u);
    *l = (unsigned short)(__float_as_uint(lo) >> 16);
}
__device__ __forceinline__ uint2 split_pack2(float f0, float f1) {
    unsigned u0 = __float_as_uint(f0), u1 = __float_as_uint(f1);
    unsigned hp = (u0 >> 16) | (u1 & 0xffff0000u);
    float l0 = f0 - __uint_as_float(u0 & 0xffff0000u);
    float l1 = f1 - __uint_as_float(u1 & 0xffff0000u);
    unsigned lp = (__float_as_uint(l0) >> 16) | (__float_as_uint(l1) & 0xffff0000u);
    return make_uint2(hp, lp);
}

// ---------------- merged prep: conv weights | shared weights | emb2bf | E ----------------
__global__ __launch_bounds__(256) void prep_kernel(
    const float* __restrict__ w0, const float* __restrict__ w1,
    const float* __restrict__ w2, const float* __restrict__ w3,
    unsigned short* __restrict__ Wch, unsigned short* __restrict__ Wcl,
    const float* __restrict__ cpr1_w, const float* __restrict__ cib_w,
    const float* __restrict__ cpr2_w, const float* __restrict__ cma_w,
    const float* __restrict__ ccf_w, const float* __restrict__ cl0_w,
    unsigned short* __restrict__ Wcomb_h, unsigned short* __restrict__ Wcomb_l,
    unsigned short* __restrict__ W2h, unsigned short* __restrict__ W2l,
    unsigned short* __restrict__ cmah, unsigned short* __restrict__ cmal,
    unsigned short* __restrict__ ccfh, unsigned short* __restrict__ ccfl,
    unsigned short* __restrict__ cl0h, unsigned short* __restrict__ cl0l,
    const float* __restrict__ emb,
    unsigned short* __restrict__ EmbHi, unsigned short* __restrict__ EmbLo,
    const float* __restrict__ ees, const float* __restrict__ cpr1_b,
    const float* __restrict__ cib_b, float* __restrict__ Eb) {
    int blk = blockIdx.x, tid = threadIdx.x;
    unsigned short h, l;
    if (blk < 768) {                    // conv weights: 4*3*128*128
        int gid = blk*256 + tid;
        int c = gid & 127;
        int o = (gid >> 7) & 127;
        int kst = gid >> 14;
        int k = kst % 3, st = kst / 3;
        const float* w = (st == 0) ? w0 : (st == 1) ? w1 : (st == 2) ? w2 : w3;
        float v = (o < CH && c < CH) ? w[o*CH*3 + c*3 + k] : 0.f;
        split1(v, &h, &l);
        Wch[gid] = h; Wcl[gid] = l;
    } else if (blk < 912) {             // shared weights: 36864
        int gid = (blk - 768)*256 + tid;
        if (gid < 8192) {
            int o = gid >> 7, c = gid & 127;
            float v = 0.f;
            if (c < CH) {
                const float* wrow = cpr1_w + o*(2*D_);
                #pragma unroll
                for (int k = 0; k < D_; ++k) v += wrow[k]*cib_w[k*CH + c];
            }
            split1(v, &h, &l); Wcomb_h[gid] = h; Wcomb_l[gid] = l;
        } else if (gid < 12288) {
            int idx = gid - 8192;
            split1(cpr2_w[idx], &h, &l); W2h[idx] = h; W2l[idx] = l;
        } else if (gid < 20480) {
            int idx = gid - 12288;
            int o = idx >> 6;
            float v = (o < CH) ? cma_w[idx] : 0.f;
            split1(v, &h, &l); cmah[idx] = h; cmal[idx] = l;
        } else if (gid < 28672) {
            int idx = gid - 20480;
            int d = idx >> 7, c = idx & 127;
            float v = (c < CH) ? ccf_w[d*CH + c] : 0.f;
            split1(v, &h, &l); ccfh[idx] = h; ccfl[idx] = l;
        } else {
            int idx = gid - 28672;
            int o = idx >> 6;
            float v = (o < CH) ? cl0_w[idx] : 0.f;
            split1(v, &h, &l); cl0h[idx] = h; cl0l[idx] = l;
        }
    } else if (blk < 1936) {            // emb -> bf16 hi/lo (per float4)
        int i = (blk - 912)*256 + tid;
        float4 v = reinterpret_cast<const float4*>(emb)[i];
        ushort4 hh, ll;
        split1(v.x, &hh.x, &ll.x);
        split1(v.y, &hh.y, &ll.y);
        split1(v.z, &hh.z, &ll.z);
        split1(v.w, &hh.w, &ll.w);
        reinterpret_cast<ushort4*>(EmbHi)[i] = hh;
        reinterpret_cast<ushort4*>(EmbLo)[i] = ll;
    } else {                            // E: 4 (b,l) groups of 64 lanes
        __shared__ float ec[4][64];
        int g = tid >> 6, c = tid & 63;
        int bl = (blk - 1936)*4 + g;
        int b = bl / SL, lq = bl % SL;
        ec[g][c] = ees[(b*D_ + c)*SL + lq];
        __syncthreads();
        const float* wrow = cpr1_w + c*(2*D_);
        float acc = cpr1_b[c];
        #pragma unroll
        for (int k = 0; k < D_; ++k) acc += wrow[k]*cib_b[k];
        #pragma unroll
        for (int cc = 0; cc < D_; ++cc) acc += wrow[D_ + cc]*ec[g][cc];
        Eb[(b*SL + lq)*D_ + c] = acc;
    }
}

// ======== h2max wave body (stride-parametrized output) ========
__device__ __forceinline__ void h2max_wave(
    const float* __restrict__ AcRow,
    const float* __restrict__ El,
    const unsigned short* __restrict__ W2h, const unsigned short* __restrict__ W2l,
    int n, int kg, int o_lane, float b2_lane,
    unsigned short* Mmh, unsigned short* Mml, int bs, int stride) {
    float4 a00 = *reinterpret_cast<const float4*>(AcRow + kg*8);
    float4 a01 = *reinterpret_cast<const float4*>(AcRow + kg*8 + 4);
    float4 a10 = *reinterpret_cast<const float4*>(AcRow + 32 + kg*8);
    float4 a11 = *reinterpret_cast<const float4*>(AcRow + 32 + kg*8 + 4);

    f32x4 acc[4][3];
    #pragma unroll
    for (int mt = 0; mt < 4; ++mt)
        #pragma unroll
        for (int lt = 0; lt < 3; ++lt)
            acc[mt][lt] = (f32x4){0.f, 0.f, 0.f, 0.f};

    #pragma unroll
    for (int kt = 0; kt < 2; ++kt) {
        int cc = kt*32 + kg*8;
        float4 aA = (kt == 0) ? a00 : a10;
        float4 aB = (kt == 0) ? a01 : a11;
        s8v a2h[4], a2l[4];
        #pragma unroll
        for (int mt = 0; mt < 4; ++mt) {
            a2h[mt] = *(const s8v*)&W2h[(mt*16 + n)*64 + cc];
            a2l[mt] = *(const s8v*)&W2l[(mt*16 + n)*64 + cc];
        }
        #pragma unroll
        for (int lt = 0; lt < 3; ++lt) {
            const float* ep = &El[(lt*16 + n)*68 + cc];
            float4 e0 = *reinterpret_cast<const float4*>(ep);
            float4 e1 = *reinterpret_cast<const float4*>(ep + 4);
            float h0 = fmaxf(aA.x + e0.x, 0.f);
            float h1 = fmaxf(aA.y + e0.y, 0.f);
            float h2 = fmaxf(aA.z + e0.z, 0.f);
            float h3 = fmaxf(aA.w + e0.w, 0.f);
            float h4 = fmaxf(aB.x + e1.x, 0.f);
            float h5 = fmaxf(aB.y + e1.y, 0.f);
            float h6 = fmaxf(aB.z + e1.z, 0.f);
            float h7 = fmaxf(aB.w + e1.w, 0.f);
            uint2 q0 = split_pack2(h0, h1);
            uint2 q1 = split_pack2(h2, h3);
            uint2 q2 = split_pack2(h4, h5);
            uint2 q3 = split_pack2(h6, h7);
            union { unsigned u[4]; s8v v; } Bh, Bl;
            Bh.u[0] = q0.x; Bh.u[1] = q1.x; Bh.u[2] = q2.x; Bh.u[3] = q3.x;
            Bl.u[0] = q0.y; Bl.u[1] = q1.y; Bl.u[2] = q2.y; Bl.u[3] = q3.y;
            #pragma unroll
            for (int mt = 0; mt < 4; ++mt) {
                acc[mt][lt] = MFMA(a2h[mt], Bh.v, acc[mt][lt]);
                acc[mt][lt] = MFMA(a2h[mt], Bl.v, acc[mt][lt]);
                acc[mt][lt] = MFMA(a2l[mt], Bh.v, acc[mt][lt]);
            }
        }
    }

    float mx[16];
    #pragma unroll
    for (int mt = 0; mt < 4; ++mt)
        #pragma unroll
        for (int r = 0; r < 4; ++r)
            mx[mt*4 + r] = fmaxf(fmaxf(acc[mt][0][r], acc[mt][1][r]), acc[mt][2][r]);
    #pragma unroll
    for (int step = 0; step < 4; ++step) {
        int msk = 1 << step;
        #pragma unroll
        for (int i = 0; i < 16; ++i)
            mx[i] = fmaxf(mx[i], __shfl_xor(mx[i], msk));
    }
    float sel = mx[0];
    #pragma unroll
    for (int i = 1; i < 16; ++i)
        sel = (n == i) ? mx[i] : sel;
    float mval = fmaxf(sel + b2_lane, 0.f);
    unsigned short mh, ml; split1(mval, &mh, &ml);
    Mmh[bs*stride + o_lane] = mh;
    Mml[bs*stride + o_lane] = ml;
}

// ---------------- stage1: gather+cl0 head, conv3+Wcomb, fused h2max (r10) ----------------
__global__ __launch_bounds__(512) void stage1_kernel(
    const int* __restrict__ x, const float* __restrict__ emb,
    const unsigned short* __restrict__ cl0h, const unsigned short* __restrict__ cl0l,
    const float* __restrict__ cl0_b,
    const unsigned short* __restrict__ Wch, const unsigned short* __restrict__ Wcl,
    const float* __restrict__ conv_b,
    const unsigned short* __restrict__ Wcombh, const unsigned short* __restrict__ Wcombl,
    const float* __restrict__ Eb,
    const unsigned short* __restrict__ W2h, const unsigned short* __restrict__ W2l,
    const float* __restrict__ cpr2_b,
    float* __restrict__ pre_d, float* __restrict__ xc_g,
    unsigned short* __restrict__ Mmh, unsigned short* __restrict__ Mml) {
    int b = blockIdx.x >> 4, s0 = (blockIdx.x & 15) << 4;
    int tid = threadIdx.x, w = tid >> 6, lane = tid & 63, n = lane & 15, kg = lane >> 4;

    __shared__ unsigned short Eg_h[18*72], Eg_l[18*72];
    __shared__ unsigned short Tt_h[18*136], Tt_l[18*136];
    __shared__ unsigned short Xt_h[16*136], Xt_l[16*136];
    __shared__ float El[48*68];
    __shared__ float AcT[16*68];

    for (int idx = tid; idx < 288; idx += 512) {
        int si = idx >> 4, c4 = (idx & 15)*4;
        int s = s0 - 2 + si;
        float4 v = make_float4(0.f, 0.f, 0.f, 0.f);
        if (s >= 0) {
            int tok = x[b*SST + s];
            v = *reinterpret_cast<const float4*>(&emb[tok*D_ + c4]);
        }
        ushort4 h, l;
        split1(v.x, &h.x, &l.x); split1(v.y, &h.y, &l.y);
        split1(v.z, &h.z, &l.z); split1(v.w, &h.w, &l.w);
        *reinterpret_cast<ushort4*>(&Eg_h[si*72 + c4]) = h;
        *reinterpret_cast<ushort4*>(&Eg_l[si*72 + c4]) = l;
        if (si >= 2) {
            pre_d[(b*D_ + c4+0)*SST + s] = v.x;
            pre_d[(b*D_ + c4+1)*SST + s] = v.y;
            pre_d[(b*D_ + c4+2)*SST + s] = v.z;
            pre_d[(b*D_ + c4+3)*SST + s] = v.w;
        }
    }
    for (int idx = tid; idx < 768; idx += 512) {
        int l = idx >> 4, c4 = (idx & 15)*4;
        *reinterpret_cast<float4*>(&El[l*68 + c4]) =
            *reinterpret_cast<const float4*>(&Eb[(b*SL + l)*64 + c4]);
    }
    __syncthreads();

    int ob = w*16 + kg*4;
    #pragma unroll
    for (int ct = 0; ct < 2; ++ct) {
        int si = ct*2 + n;
        f32x4 tv = {0.f, 0.f, 0.f, 0.f};
        #pragma unroll
        for (int kt = 0; kt < 2; ++kt) {
            int cc = kt*32 + kg*8;
            s8v bh = *(const s8v*)&Eg_h[si*72 + cc];
            s8v bl = *(const s8v*)&Eg_l[si*72 + cc];
            int ai = (w*16 + n)*64 + cc;
            s8v ah = *(const s8v*)&cl0h[ai];
            s8v al = *(const s8v*)&cl0l[ai];
            tv = MFMA(ah, bh, tv); tv = MFMA(ah, bl, tv); tv = MFMA(al, bh, tv);
        }
        int s = s0 - 2 + si;
        float r0 = 0.f, r1 = 0.f, r2 = 0.f, r3 = 0.f;
        if (s >= 0) {
            r0 = tv[0] + ((ob+0 < CH) ? cl0_b[ob+0] : 0.f);
            r1 = tv[1] + ((ob+1 < CH) ? cl0_b[ob+1] : 0.f);
            r2 = tv[2] + ((ob+2 < CH) ? cl0_b[ob+2] : 0.f);
            r3 = tv[3] + ((ob+3 < CH) ? cl0_b[ob+3] : 0.f);
        }
        uint2 p01 = split_pack2(r0, r1), p23 = split_pack2(r2, r3);
        *reinterpret_cast<uint2*>(&Tt_h[si*136 + ob]) = make_uint2(p01.x, p23.x);
        *reinterpret_cast<uint2*>(&Tt_l[si*136 + ob]) = make_uint2(p01.y, p23.y);
    }
    __syncthreads();

    f32x4 xcv = {0.f, 0.f, 0.f, 0.f};
    #pragma unroll
    for (int k = 0; k < 3; ++k)
        #pragma unroll
        for (int kt = 0; kt < 4; ++kt) {
            int cc = kt*32 + kg*8;
            s8v bh = *(const s8v*)&Tt_h[(n + k)*136 + cc];
            s8v bl = *(const s8v*)&Tt_l[(n + k)*136 + cc];
            int ai = (k*128 + w*16 + n)*128 + cc;
            s8v ah = *(const s8v*)&Wch[ai];
            s8v al = *(const s8v*)&Wcl[ai];
            xcv = MFMA(ah, bh, xcv); xcv = MFMA(ah, bl, xcv); xcv = MFMA(al, bh, xcv);
        }
    #pragma unroll
    for (int r = 0; r < 4; ++r) {
        float cb = (ob + r < CH) ? conv_b[ob + r] : 0.f;
        xcv[r] = fmaxf(xcv[r] + cb, 0.f);
    }
    {
        uint2 p01 = split_pack2(xcv[0], xcv[1]), p23 = split_pack2(xcv[2], xcv[3]);
        *reinterpret_cast<uint2*>(&Xt_h[n*136 + ob]) = make_uint2(p01.x, p23.x);
        *reinterpret_cast<uint2*>(&Xt_l[n*136 + ob]) = make_uint2(p01.y, p23.y);
        *reinterpret_cast<float4*>(&xc_g[(b*SST + s0 + n)*128 + ob]) =
            make_float4(xcv[0], xcv[1], xcv[2], xcv[3]);
    }
    __syncthreads();

    if (w < 4) {
        f32x4 acc = {0.f, 0.f, 0.f, 0.f};
        #pragma unroll
        for (int kt = 0; kt < 4; ++kt) {
            int cc = kt*32 + kg*8;
            int ai = (w*16 + n)*128 + cc;
            s8v ah = *(const s8v*)&Wcombh[ai];
            s8v al = *(const s8v*)&Wcombl[ai];
            s8v bh = *(const s8v*)&Xt_h[n*136 + cc];
            s8v bl = *(const s8v*)&Xt_l[n*136 + cc];
            acc = MFMA(ah, bh, acc); acc = MFMA(ah, bl, acc); acc = MFMA(al, bh, acc);
        }
        *reinterpret_cast<float4*>(&AcT[n*68 + w*16 + kg*4]) =
            make_float4(acc[0], acc[1], acc[2], acc[3]);
    }
    __syncthreads();

    int o_lane = ((n >> 2) << 4) + (kg << 2) + (n & 3);
    float b2_lane = cpr2_b[o_lane];
    #pragma unroll
    for (int si = 0; si < 2; ++si) {
        int s = w*2 + si;
        h2max_wave(&AcT[s*68], El, W2h, W2l, n, kg, o_lane, b2_lane,
                   Mmh, Mml, b*SST + s0 + s, 64);
    }
}

// ---------------- stageM: cma@Mm+xc head, conv3+Wcomb, fused h2max (r10) ----------------
__global__ __launch_bounds__(512) void stagem_kernel(
    const unsigned short* __restrict__ Mmh_in, const unsigned short* __restrict__ Mml_in,
    const unsigned short* __restrict__ cmah, const unsigned short* __restrict__ cmal,
    const float* __restrict__ cma_b, const float* __restrict__ xc_prev,
    const unsigned short* __restrict__ Wch, const unsigned short* __restrict__ Wcl,
    const float* __restrict__ conv_b,
    const unsigned short* __restrict__ Wcombh, const unsigned short* __restrict__ Wcombl,
    const float* __restrict__ Eb,
    const unsigned short* __restrict__ W2h, const unsigned short* __restrict__ W2l,
    const float* __restrict__ cpr2_b,
    float* __restrict__ xc_g,
    unsigned short* __restrict__ Mmh_out, unsigned short* __restrict__ Mml_out) {
    int b = blockIdx.x >> 4, s0 = (blockIdx.x & 15) << 4;
    int tid = threadIdx.x, w = tid >> 6, lane = tid & 63, n = lane & 15, kg = lane >> 4;

    __shared__ unsigned short Eg_h[18*72], Eg_l[18*72];
    __shared__ unsigned short Tt_h[18*136], Tt_l[18*136];
    __shared__ unsigned short Xt_h[16*136], Xt_l[16*136];
    __shared__ float El[48*68];
    __shared__ float AcT[16*68];

    for (int idx = tid; idx < 288; idx += 512) {
        int si = idx >> 4, c4 = (idx & 15)*4;
        int s = s0 - 2 + si;
        uint2 h = make_uint2(0, 0), l = make_uint2(0, 0);
        if (s >= 0) {
            h = *reinterpret_cast<const uint2*>(&Mmh_in[(b*SST + s)*64 + c4]);
            l = *reinterpret_cast<const uint2*>(&Mml_in[(b*SST + s)*64 + c4]);
        }
        *reinterpret_cast<uint2*>(&Eg_h[si*72 + c4]) = h;
        *reinterpret_cast<uint2*>(&Eg_l[si*72 + c4]) = l;
    }
    for (int idx = tid; idx < 768; idx += 512) {
        int l = idx >> 4, c4 = (idx & 15)*4;
        *reinterpret_cast<float4*>(&El[l*68 + c4]) =
            *reinterpret_cast<const float4*>(&Eb[(b*SL + l)*64 + c4]);
    }
    __syncthreads();

    int ob = w*16 + kg*4;
    #pragma unroll
    for (int ct = 0; ct < 2; ++ct) {
        int si = ct*2 + n;
        f32x4 tv = {0.f, 0.f, 0.f, 0.f};
        #pragma unroll
        for (int kt = 0; kt < 2; ++kt) {
            int cc = kt*32 + kg*8;
            s8v bh = *(const s8v*)&Eg_h[si*72 + cc];
            s8v bl = *(const s8v*)&Eg_l[si*72 + cc];
            int ai = (w*16 + n)*64 + cc;
            s8v ah = *(const s8v*)&cmah[ai];
            s8v al = *(const s8v*)&cmal[ai];
            tv = MFMA(ah, bh, tv); tv = MFMA(ah, bl, tv); tv = MFMA(al, bh, tv);
        }
        int s = s0 - 2 + si;
        float r0 = 0.f, r1 = 0.f, r2 = 0.f, r3 = 0.f;
        if (s >= 0) {
            float4 xr = *reinterpret_cast<const float4*>(&xc_prev[(b*SST + s)*128 + ob]);
            r0 = tv[0] + ((ob+0 < CH) ? cma_b[ob+0] : 0.f) + xr.x;
            r1 = tv[1] + ((ob+1 < CH) ? cma_b[ob+1] : 0.f) + xr.y;
            r2 = tv[2] + ((ob+2 < CH) ? cma_b[ob+2] : 0.f) + xr.z;
            r3 = tv[3] + ((ob+3 < CH) ? cma_b[ob+3] : 0.f) + xr.w;
        }
        uint2 p01 = split_pack2(r0, r1), p23 = split_pack2(r2, r3);
        *reinterpret_cast<uint2*>(&Tt_h[si*136 + ob]) = make_uint2(p01.x, p23.x);
        *reinterpret_cast<uint2*>(&Tt_l[si*136 + ob]) = make_uint2(p01.y, p23.y);
    }
    __syncthreads();

    f32x4 xcv = {0.f, 0.f, 0.f, 0.f};
    #pragma unroll
    for (int k = 0; k < 3; ++k)
        #pragma unroll
        for (int kt = 0; kt < 4; ++kt) {
            int cc = kt*32 + kg*8;
            s8v bh = *(const s8v*)&Tt_h[(n + k)*136 + cc];
            s8v bl = *(const s8v*)&Tt_l[(n + k)*136 + cc];
            int ai = (k*128 + w*16 + n)*128 + cc;
            s8v ah = *(const s8v*)&Wch[ai];
            s8v al = *(const s8v*)&Wcl[ai];
            xcv = MFMA(ah, bh, xcv); xcv = MFMA(ah, bl, xcv); xcv = MFMA(al, bh, xcv);
        }
    #pragma unroll
    for (int r = 0; r < 4; ++r) {
        float cb = (ob + r < CH) ? conv_b[ob + r] : 0.f;
        xcv[r] = fmaxf(xcv[r] + cb, 0.f);
    }
    {
        uint2 p01 = split_pack2(xcv[0], xcv[1]), p23 = split_pack2(xcv[2], xcv[3]);
        *reinterpret_cast<uint2*>(&Xt_h[n*136 + ob]) = make_uint2(p01.x, p23.x);
        *reinterpret_cast<uint2*>(&Xt_l[n*136 + ob]) = make_uint2(p01.y, p23.y);
        *reinterpret_cast<float4*>(&xc_g[(b*SST + s0 + n)*128 + ob]) =
            make_float4(xcv[0], xcv[1], xcv[2], xcv[3]);
    }
    __syncthreads();

    if (w < 4) {
        f32x4 acc = {0.f, 0.f, 0.f, 0.f};
        #pragma unroll
        for (int kt = 0; kt < 4; ++kt) {
            int cc = kt*32 + kg*8;
            int ai = (w*16 + n)*128 + cc;
            s8v ah = *(const s8v*)&Wcombh[ai];
            s8v al = *(const s8v*)&Wcombl[ai];
            s8v bh = *(const s8v*)&Xt_h[n*136 + cc];
            s8v bl = *(const s8v*)&Xt_l[n*136 + cc];
            acc = MFMA(ah, bh, acc); acc = MFMA(ah, bl, acc); acc = MFMA(al, bh, acc);
        }
        *reinterpret_cast<float4*>(&AcT[n*68 + w*16 + kg*4]) =
            make_float4(acc[0], acc[1], acc[2], acc[3]);
    }
    __syncthreads();

    int o_lane = ((n >> 2) << 4) + (kg << 2) + (n & 3);
    float b2_lane = cpr2_b[o_lane];
    #pragma unroll
    for (int si = 0; si < 2; ++si) {
        int s = w*2 + si;
        h2max_wave(&AcT[s*68], El, W2h, W2l, n, kg, o_lane, b2_lane,
                   Mmh_out, Mml_out, b*SST + s0 + s, 64);
    }
}

// ------- stage4: stageM body + fused cmaccf tail (Mm in LDS, xcv in regs) -------
__global__ __launch_bounds__(512) void stage4_kernel(
    const unsigned short* __restrict__ Mmh_in, const unsigned short* __restrict__ Mml_in,
    const unsigned short* __restrict__ cmah, const unsigned short* __restrict__ cmal,
    const float* __restrict__ cma_b, const float* __restrict__ xc_prev,
    const unsigned short* __restrict__ Wch, const unsigned short* __restrict__ Wcl,
    const float* __restrict__ conv_b,
    const unsigned short* __restrict__ Wcombh, const unsigned short* __restrict__ Wcombl,
    const float* __restrict__ Eb,
    const unsigned short* __restrict__ W2h, const unsigned short* __restrict__ W2l,
    const float* __restrict__ cpr2_b,
    const unsigned short* __restrict__ ccfh, const unsigned short* __restrict__ ccfl,
    const float* __restrict__ ccf_b,
    float* __restrict__ ccf_out,
    unsigned short* __restrict__ Ahi, unsigned short* __restrict__ Alo) {
    int b = blockIdx.x >> 4, s0 = (blockIdx.x & 15) << 4;
    int tid = threadIdx.x, w = tid >> 6, lane = tid & 63, n = lane & 15, kg = lane >> 4;

    __shared__ unsigned short Eg_h[18*72], Eg_l[18*72];    // reused as Mm LDS later
    __shared__ unsigned short Tt_h[18*136], Tt_l[18*136];  // reused as t4 LDS later
    __shared__ unsigned short Xt_h[16*136], Xt_l[16*136];
    __shared__ float El[48*68];
    __shared__ float AcT[16*68];

    for (int idx = tid; idx < 288; idx += 512) {
        int si = idx >> 4, c4 = (idx & 15)*4;
        int s = s0 - 2 + si;
        uint2 h = make_uint2(0, 0), l = make_uint2(0, 0);
        if (s >= 0) {
            h = *reinterpret_cast<const uint2*>(&Mmh_in[(b*SST + s)*64 + c4]);
            l = *reinterpret_cast<const uint2*>(&Mml_in[(b*SST + s)*64 + c4]);
        }
        *reinterpret_cast<uint2*>(&Eg_h[si*72 + c4]) = h;
        *reinterpret_cast<uint2*>(&Eg_l[si*72 + c4]) = l;
    }
    for (int idx = tid; idx < 768; idx += 512) {
        int l = idx >> 4, c4 = (idx & 15)*4;
        *reinterpret_cast<float4*>(&El[l*68 + c4]) =
            *reinterpret_cast<const float4*>(&Eb[(b*SL + l)*64 + c4]);
    }
    __syncthreads();

    int ob = w*16 + kg*4;
    #pragma unroll
    for (int ct = 0; ct < 2; ++ct) {
        int si = ct*2 + n;
        f32x4 tv = {0.f, 0.f, 0.f, 0.f};
        #pragma unroll
        for (int kt = 0; kt < 2; ++kt) {
            int cc = kt*32 + kg*8;
            s8v bh = *(const s8v*)&Eg_h[si*72 + cc];
            s8v bl = *(const s8v*)&Eg_l[si*72 + cc];
            int ai = (w*16 + n)*64 + cc;
            s8v ah = *(const s8v*)&cmah[ai];
            s8v al = *(const s8v*)&cmal[ai];
            tv = MFMA(ah, bh, tv); tv = MFMA(ah, bl, tv); tv = MFMA(al, bh, tv);
        }
        int s = s0 - 2 + si;
        float r0 = 0.f, r1 = 0.f, r2 = 0.f, r3 = 0.f;
        if (s >= 0) {
            float4 xr = *reinterpret_cast<const float4*>(&xc_prev[(b*SST + s)*128 + ob]);
            r0 = tv[0] + ((ob+0 < CH) ? cma_b[ob+0] : 0.f) + xr.x;
            r1 = tv[1] + ((ob+1 < CH) ? cma_b[ob+1] : 0.f) + xr.y;
            r2 = tv[2] + ((ob+2 < CH) ? cma_b[ob+2] : 0.f) + xr.z;
            r3 = tv[3] + ((ob+3 < CH) ? cma_b[ob+3] : 0.f) + xr.w;
        }
        uint2 p01 = split_pack2(r0, r1), p23 = split_pack2(r2, r3);
        *reinterpret_cast<uint2*>(&Tt_h[si*136 + ob]) = make_uint2(p01.x, p23.x);
        *reinterpret_cast<uint2*>(&Tt_l[si*136 + ob]) = make_uint2(p01.y, p23.y);
    }
    __syncthreads();

    f32x4 xcv = {0.f, 0.f, 0.f, 0.f};
    #pragma unroll
    for (int k = 0; k < 3; ++k)
        #pragma unroll
        for (int kt = 0; kt < 4; ++kt) {
            int cc = kt*32 + kg*8;
            s8v bh = *(const s8v*)&Tt_h[(n + k)*136 + cc];
            s8v bl = *(const s8v*)&Tt_l[(n + k)*136 + cc];
            int ai = (k*128 + w*16 + n)*128 + cc;
            s8v ah = *(const s8v*)&Wch[ai];
            s8v al = *(const s8v*)&Wcl[ai];
            xcv = MFMA(ah, bh, xcv); xcv = MFMA(ah, bl, xcv); xcv = MFMA(al, bh, xcv);
        }
    #pragma unroll
    for (int r = 0; r < 4; ++r) {
        float cb = (ob + r < CH) ? conv_b[ob + r] : 0.f;
        xcv[r] = fmaxf(xcv[r] + cb, 0.f);
    }
    {
        uint2 p01 = split_pack2(xcv[0], xcv[1]), p23 = split_pack2(xcv[2], xcv[3]);
        *reinterpret_cast<uint2*>(&Xt_h[n*136 + ob]) = make_uint2(p01.x, p23.x);
        *reinterpret_cast<uint2*>(&Xt_l[n*136 + ob]) = make_uint2(p01.y, p23.y);
        // no xc_g global store: consumed in-registers by the t4 tail below
    }
    __syncthreads();

    if (w < 4) {
        f32x4 acc = {0.f, 0.f, 0.f, 0.f};
        #pragma unroll
        for (int kt = 0; kt < 4; ++kt) {
            int cc = kt*32 + kg*8;
            int ai = (w*16 + n)*128 + cc;
            s8v ah = *(const s8v*)&Wcombh[ai];
            s8v al = *(const s8v*)&Wcombl[ai];
            s8v bh = *(const s8v*)&Xt_h[n*136 + cc];
            s8v bl = *(const s8v*)&Xt_l[n*136 + cc];
            acc = MFMA(ah, bh, acc); acc = MFMA(ah, bl, acc); acc = MFMA(al, bh, acc);
        }
        *reinterpret_cast<float4*>(&AcT[n*68 + w*16 + kg*4]) =
            make_float4(acc[0], acc[1], acc[2], acc[3]);
    }
    __syncthreads();

    // h2max -> Mm in LDS (reuse Eg space; stride 72, local s index)
    int o_lane = ((n >> 2) << 4) + (kg << 2) + (n & 3);
    float b2_lane = cpr2_b[o_lane];
    #pragma unroll
    for (int si = 0; si < 2; ++si) {
        int s = w*2 + si;
        h2max_wave(&AcT[s*68], El, W2h, W2l, n, kg, o_lane, b2_lane,
                   Eg_h, Eg_l, s, 72);
    }
    __syncthreads();

    // t4 = cma @ Mm + cma_b + xconv  (wave w -> o-tile w; col = n) -> Tt reuse
    {
        f32x4 tv = {0.f, 0.f, 0.f, 0.f};
        #pragma unroll
        for (int kt = 0; kt < 2; ++kt) {
            int cc = kt*32 + kg*8;
            s8v bh = *(const s8v*)&Eg_h[n*72 + cc];
            s8v bl = *(const s8v*)&Eg_l[n*72 + cc];
            int ai = (w*16 + n)*64 + cc;
            s8v ah = *(const s8v*)&cmah[ai];
            s8v al = *(const s8v*)&cmal[ai];
            tv = MFMA(ah, bh, tv); tv = MFMA(ah, bl, tv); tv = MFMA(al, bh, tv);
        }
        float r0 = tv[0] + ((ob+0 < CH) ? cma_b[ob+0] : 0.f) + xcv[0];
        float r1 = tv[1] + ((ob+1 < CH) ? cma_b[ob+1] : 0.f) + xcv[1];
        float r2 = tv[2] + ((ob+2 < CH) ? cma_b[ob+2] : 0.f) + xcv[2];
        float r3 = tv[3] + ((ob+3 < CH) ? cma_b[ob+3] : 0.f) + xcv[3];
        uint2 p01 = split_pack2(r0, r1), p23 = split_pack2(r2, r3);
        *reinterpret_cast<uint2*>(&Tt_h[n*136 + ob]) = make_uint2(p01.x, p23.x);
        *reinterpret_cast<uint2*>(&Tt_l[n*136 + ob]) = make_uint2(p01.y, p23.y);
    }
    __syncthreads();

    // ccf = ccf_w @ t4 + ccf_b  (waves 0-3, d-tile w)
    if (w < 4) {
        f32x4 acc = {0.f, 0.f, 0.f, 0.f};
        #pragma unroll
        for (int kt = 0; kt < 4; ++kt) {
            int cc = kt*32 + kg*8;
            int ai = (w*16 + n)*128 + cc;
            s8v ah = *(const s8v*)&ccfh[ai];
            s8v al = *(const s8v*)&ccfl[ai];
            s8v bh = *(const s8v*)&Tt_h[n*136 + cc];
            s8v bl = *(const s8v*)&Tt_l[n*136 + cc];
            acc = MFMA(ah, bh, acc); acc = MFMA(ah, bl, acc); acc = MFMA(al, bh, acc);
        }
        int d0 = w*16 + kg*4, s = s0 + n;
        float v0 = acc[0] + ccf_b[d0+0];
        float v1 = acc[1] + ccf_b[d0+1];
        float v2 = acc[2] + ccf_b[d0+2];
        float v3 = acc[3] + ccf_b[d0+3];
        ccf_out[(b*D_ + d0+0)*SST + s] = v0;
        ccf_out[(b*D_ + d0+1)*SST + s] = v1;
        ccf_out[(b*D_ + d0+2)*SST + s] = v2;
        ccf_out[(b*D_ + d0+3)*SST + s] = v3;
        uint2 p01 = split_pack2(v0, v1), p23 = split_pack2(v2, v3);
        *reinterpret_cast<uint2*>(&Ahi[(b*SST + s)*64 + d0]) = make_uint2(p01.x, p23.x);
        *reinterpret_cast<uint2*>(&Alo[(b*SST + s)*64 + d0]) = make_uint2(p01.y, p23.y);
    }
}

// ---------------- logits: r10-best (plain stores, ni-innermost) ----------------
__global__ __launch_bounds__(256) void logits_mfma_kernel(
    const unsigned short* __restrict__ Ahi,
    const unsigned short* __restrict__ Alo,
    const unsigned short* __restrict__ Bhi,
    const unsigned short* __restrict__ Blo,
    const float* __restrict__ fffb,
    float* __restrict__ out) {
    int ntile = blockIdx.x & 127;
    int mtile = blockIdx.x >> 7;
    int wid = threadIdx.x >> 6;
    int lane = threadIdx.x & 63;
    int wm = wid >> 1, wn = wid & 1;
    int m0 = mtile*128 + wm*64;
    int v0 = ntile*128 + wn*64;
    int row16 = lane & 15, kg = lane >> 4;

    const short* Ah = (const short*)Ahi;
    const short* Al = (const short*)Alo;
    const short* Bh = (const short*)Bhi;
    const short* Bl = (const short*)Blo;

    f32x4 acc[4][4];
    #pragma unroll
    for (int mi = 0; mi < 4; ++mi)
        #pragma unroll
        for (int ni = 0; ni < 4; ++ni)
            acc[mi][ni] = (f32x4){0.f, 0.f, 0.f, 0.f};

    #pragma unroll
    for (int kk = 0; kk < 2; ++kk) {
        int koff = kk*32 + kg*8;
        s8v ah[4], al[4], bh[4], bl[4];
        #pragma unroll
        for (int mi = 0; mi < 4; ++mi) {
            int r = (m0 + mi*16 + row16)*D_ + koff;
            ah[mi] = *reinterpret_cast<const s8v*>(Ah + r);
            al[mi] = *reinterpret_cast<const s8v*>(Al + r);
        }
        #pragma unroll
        for (int ni = 0; ni < 4; ++ni) {
            int r = (v0 + ni*16 + row16)*D_ + koff;
            bh[ni] = *reinterpret_cast<const s8v*>(Bh + r);
            bl[ni] = *reinterpret_cast<const s8v*>(Bl + r);
        }
        #pragma unroll
        for (int mi = 0; mi < 4; ++mi)
            #pragma unroll
            for (int ni = 0; ni < 4; ++ni) {
                acc[mi][ni] = MFMA(ah[mi], bh[ni], acc[mi][ni]);
                acc[mi][ni] = MFMA(ah[mi], bl[ni], acc[mi][ni]);
                acc[mi][ni] = MFMA(al[mi], bh[ni], acc[mi][ni]);
            }
    }

    float fb[4];
    #pragma unroll
    for (int ni = 0; ni < 4; ++ni) fb[ni] = fffb[v0 + ni*16 + row16];

    #pragma unroll
    for (int mi = 0; mi < 4; ++mi) {
        #pragma unroll
        for (int r = 0; r < 4; ++r) {
            size_t rowbase = (size_t)(m0 + mi*16 + kg*4 + r)*VOCAB;
            #pragma unroll
            for (int ni = 0; ni < 4; ++ni) {
                out[rowbase + v0 + ni*16 + row16] = acc[mi][ni][r] + fb[ni];
            }
        }
    }
}

extern "C" void kernel_launch(void* const* d_in, const int* in_sizes, int n_in,
                              void* d_out, int out_size, void* d_ws, size_t ws_size,
                              hipStream_t stream) {
    const int*   x     = (const int*)d_in[0];
    const float* ees   = (const float*)d_in[1];
    const float* emb   = (const float*)d_in[2];
    const float* cl0_w = (const float*)d_in[3];
    const float* cl0_b = (const float*)d_in[4];
    const float* cl1_w = (const float*)d_in[5];
    const float* cl1_b = (const float*)d_in[6];
    const float* claa_w= (const float*)d_in[7];
    const float* claa_b= (const float*)d_in[8];
    const float* clfa_w= (const float*)d_in[9];
    const float* clfa_b= (const float*)d_in[10];
    const float* ccac_w= (const float*)d_in[11];
    const float* ccac_b= (const float*)d_in[12];
    const float* cib_w = (const float*)d_in[13];
    const float* cib_b = (const float*)d_in[14];
    const float* cpr1_w= (const float*)d_in[15];
    const float* cpr1_b= (const float*)d_in[16];
    const float* cpr2_w= (const float*)d_in[17];
    const float* cpr2_b= (const float*)d_in[18];
    const float* cma_w = (const float*)d_in[19];
    const float* cma_b = (const float*)d_in[20];
    const float* ccf_w = (const float*)d_in[21];
    const float* ccf_b = (const float*)d_in[22];
    const float* fff_b = (const float*)d_in[23];

    float* out = (float*)d_out;
    float* out_pre = out + OUT0_ELEMS;
    float* out_ccf = out_pre + OUT1_ELEMS;

    unsigned short* EmbHi = (unsigned short*)d_ws;
    unsigned short* EmbLo = EmbHi + VOCAB*D_;
    unsigned short* Ahi   = EmbLo + VOCAB*D_;
    unsigned short* Alo   = Ahi + B_*SST*D_;

    char* sc = (char*)d_out + (size_t)16*1024*1024;
    float*          Eb    = (float*)sc;            sc += B_*SL*D_*4;
    unsigned short* Wch   = (unsigned short*)sc;   sc += 4*3*128*128*2;
    unsigned short* Wcl   = (unsigned short*)sc;   sc += 4*3*128*128*2;
    unsigned short* Wcombh= (unsigned short*)sc;   sc += 64*128*2;
    unsigned short* Wcombl= (unsigned short*)sc;   sc += 64*128*2;
    unsigned short* W2h   = (unsigned short*)sc;   sc += 64*64*2;
    unsigned short* W2l   = (unsigned short*)sc;   sc += 64*64*2;
    unsigned short* cmah  = (unsigned short*)sc;   sc += 128*64*2;
    unsigned short* cmal  = (unsigned short*)sc;   sc += 128*64*2;
    unsigned short* ccfh  = (unsigned short*)sc;   sc += 64*128*2;
    unsigned short* ccfl  = (unsigned short*)sc;   sc += 64*128*2;
    unsigned short* cl0h  = (unsigned short*)sc;   sc += 128*64*2;
    unsigned short* cl0l  = (unsigned short*)sc;   sc += 128*64*2;
    float*          xc_a  = (float*)sc;            sc += (size_t)B_*SST*128*4;
    float*          xc_b  = (float*)sc;            sc += (size_t)B_*SST*128*4;
    unsigned short* Mmh   = (unsigned short*)sc;   sc += B_*SST*64*2;
    unsigned short* Mml   = (unsigned short*)sc;   sc += B_*SST*64*2;

    // merged prep: conv(768) | shared(144) | emb2bf(1024) | E(192)
    prep_kernel<<<2128, 256, 0, stream>>>(
        cl1_w, claa_w, clfa_w, ccac_w, Wch, Wcl,
        cpr1_w, cib_w, cpr2_w, cma_w, ccf_w, cl0_w,
        Wcombh, Wcombl, W2h, W2l, cmah, cmal, ccfh, ccfl, cl0h, cl0l,
        emb, EmbHi, EmbLo,
        ees, cpr1_b, cib_b, Eb);

    stage1_kernel<<<256, 512, 0, stream>>>(x, emb, cl0h, cl0l, cl0_b,
        Wch + 0*WCS, Wcl + 0*WCS, cl1_b, Wcombh, Wcombl, Eb, W2h, W2l, cpr2_b,
        out_pre, xc_a, Mmh, Mml);
    stagem_kernel<<<256, 512, 0, stream>>>(Mmh, Mml, cmah, cmal, cma_b, xc_a,
        Wch + 1*WCS, Wcl + 1*WCS, claa_b, Wcombh, Wcombl, Eb, W2h, W2l, cpr2_b,
        xc_b, Mmh, Mml);
    stagem_kernel<<<256, 512, 0, stream>>>(Mmh, Mml, cmah, cmal, cma_b, xc_b,
        Wch + 2*WCS, Wcl + 2*WCS, clfa_b, Wcombh, Wcombl, Eb, W2h, W2l, cpr2_b,
        xc_a, Mmh, Mml);
    stage4_kernel<<<256, 512, 0, stream>>>(Mmh, Mml, cmah, cmal, cma_b, xc_a,
        Wch + 3*WCS, Wcl + 3*WCS, ccac_b, Wcombh, Wcombl, Eb, W2h, W2l, cpr2_b,
        ccfh, ccfl, ccf_b, out_ccf, Ahi, Alo);

    logits_mfma_kernel<<<(B_*SST/128)*(VOCAB/128), 256, 0, stream>>>(
        Ahi, Alo, EmbHi, EmbLo, fff_b, out);
}